// Round 1
// baseline (8223.341 us; speedup 1.0000x reference)
//
#include <hip/hip_runtime.h>
#include <hip/hip_bf16.h>

#define B_   128
#define L_   512
#define E_   512
#define H_   256
#define K_   64
#define G4H  1024   // 4*H

typedef __bf16 bf16x8 __attribute__((ext_vector_type(8)));
typedef float  f32x4  __attribute__((ext_vector_type(4)));

__device__ inline unsigned short f2bf(float f) {
    unsigned int x = __builtin_bit_cast(unsigned int, f);
    unsigned int r = (x + 0x7fffu + ((x >> 16) & 1u)) >> 16;
    return (unsigned short)r;
}
__device__ inline float bf2f(unsigned short u) {
    unsigned int x = ((unsigned int)u) << 16;
    return __builtin_bit_cast(float, x);
}
__device__ inline unsigned int pack2(float lo, float hi) {
    return (unsigned int)f2bf(lo) | ((unsigned int)f2bf(hi) << 16);
}
__device__ inline float sigm(float x) { return 1.f / (1.f + __expf(-x)); }
__device__ inline float tanh_f(float x) { return 2.f / (1.f + __expf(-2.f * x)) - 1.f; }

// ---------------------------------------------------------------------------
// Setup: convert w_hh (both dirs), w_emit to bf16; bias_cat = b_ih + b_hh
// ---------------------------------------------------------------------------
__global__ void setup_convert(const float* __restrict__ whh_f, const float* __restrict__ whh_b,
                              const float* __restrict__ wemit,
                              const float* __restrict__ bihf, const float* __restrict__ bhhf,
                              const float* __restrict__ bihb, const float* __restrict__ bhhb,
                              unsigned short* __restrict__ whh_bf,
                              unsigned short* __restrict__ wemit_bf,
                              float* __restrict__ bias_cat) {
    int i = blockIdx.x * 256 + threadIdx.x;
    const int nwhh = 2 * G4H * H_;              // 524288
    if (i < nwhh) {
        float v = (i < G4H * H_) ? whh_f[i] : whh_b[i - G4H * H_];
        whh_bf[i] = f2bf(v);
    }
    if (i < K_ * 2 * H_) wemit_bf[i] = f2bf(wemit[i]);
    if (i < 2 * G4H) {
        bias_cat[i] = (i < G4H) ? (bihf[i] + bhhf[i]) : (bihb[i - G4H] + bhhb[i - G4H]);
    }
}

// ---------------------------------------------------------------------------
// pre[d][l][b][g] = x[b][l][:] . w_ih_d[g][:] + b_ih_d[g] + b_hh_d[g]   (bf16)
// M = L*B (m = l*128+b), N = 2048 (d*1024+g), K = 512.  64x64 tiles.
// ---------------------------------------------------------------------------
__global__ __launch_bounds__(256) void pre_gemm(
    const float* __restrict__ x,       // (B,L,E)
    const float* __restrict__ wihf,    // (1024,512)
    const float* __restrict__ wihb,    // (1024,512)
    const float* __restrict__ bias_cat,// (2048)
    unsigned short* __restrict__ pre)  // [2][L][B][1024] bf16
{
    __shared__ unsigned short lds_a[64][40];   // 32 K-slice + 8 pad
    __shared__ unsigned short lds_b[64][40];

    int nt = blockIdx.x, mt = blockIdx.y;
    int tid = threadIdx.x;
    int n0 = nt * 64;
    int m0 = mt * 64;
    int l      = m0 >> 7;
    int b_base = m0 & 127;
    const float* wsrc = (n0 < 1024) ? (wihf + (size_t)n0 * E_) : (wihb + (size_t)(n0 - 1024) * E_);

    int w    = tid >> 6;
    int lane = tid & 63;
    int quad = lane >> 4, ln = lane & 15;
    int wm = (w >> 1) * 32, wn = (w & 1) * 32;

    f32x4 acc[2][2];
    #pragma unroll
    for (int i = 0; i < 2; ++i)
        #pragma unroll
        for (int j = 0; j < 2; ++j) acc[i][j] = (f32x4){0.f, 0.f, 0.f, 0.f};

    int r  = tid >> 2;          // staging row 0..63
    int kk = (tid & 3) * 8;     // staging k offset

    const float* arow = x + (size_t)(b_base + r) * L_ * E_ + (size_t)l * E_;
    const float* brow = wsrc + (size_t)r * E_;

    for (int kc = 0; kc < 16; ++kc) {
        int k0 = kc * 32;
        float4 a0 = *reinterpret_cast<const float4*>(arow + k0 + kk);
        float4 a1 = *reinterpret_cast<const float4*>(arow + k0 + kk + 4);
        float4 b0 = *reinterpret_cast<const float4*>(brow + k0 + kk);
        float4 b1 = *reinterpret_cast<const float4*>(brow + k0 + kk + 4);
        __syncthreads();   // WAR: previous iter frag reads done
        uint4 pa = { pack2(a0.x, a0.y), pack2(a0.z, a0.w), pack2(a1.x, a1.y), pack2(a1.z, a1.w) };
        uint4 pb = { pack2(b0.x, b0.y), pack2(b0.z, b0.w), pack2(b1.x, b1.y), pack2(b1.z, b1.w) };
        *reinterpret_cast<uint4*>(&lds_a[r][kk]) = pa;
        *reinterpret_cast<uint4*>(&lds_b[r][kk]) = pb;
        __syncthreads();

        bf16x8 af[2], bfv[2];
        #pragma unroll
        for (int ms = 0; ms < 2; ++ms)
            af[ms] = *reinterpret_cast<const bf16x8*>(&lds_a[wm + ms * 16 + ln][quad * 8]);
        #pragma unroll
        for (int ns = 0; ns < 2; ++ns)
            bfv[ns] = *reinterpret_cast<const bf16x8*>(&lds_b[wn + ns * 16 + ln][quad * 8]);
        #pragma unroll
        for (int ms = 0; ms < 2; ++ms)
            #pragma unroll
            for (int ns = 0; ns < 2; ++ns)
                acc[ms][ns] = __builtin_amdgcn_mfma_f32_16x16x32_bf16(af[ms], bfv[ns], acc[ms][ns], 0, 0, 0);
    }

    int dsel = n0 >> 10;
    #pragma unroll
    for (int ns = 0; ns < 2; ++ns) {
        int n = n0 + wn + ns * 16 + ln;
        float bias = bias_cat[n];
        int g = n & 1023;
        #pragma unroll
        for (int ms = 0; ms < 2; ++ms) {
            #pragma unroll
            for (int rg = 0; rg < 4; ++rg) {
                int m = m0 + wm + ms * 16 + quad * 4 + rg;
                int ll = m >> 7, bidx = m & 127;
                float v = acc[ms][ns][rg] + bias;
                pre[(((size_t)dsel * L_ + ll) * B_ + bidx) * G4H + g] = f2bf(v);
            }
        }
    }
}

// ---------------------------------------------------------------------------
// LSTM scan. 16 WGs: d = wg>>3, batch rows b0 = (wg&7)*16 .. +15.
// Per step: G(16x1024) = h(16x256) @ W_hh^T, gates, c/h update.
// Wave w owns N-tiles {w+4a+16g}: self-contained i,f,g,o per hidden group.
// ---------------------------------------------------------------------------
__global__ __launch_bounds__(256, 1) void lstm_scan(
    const unsigned short* __restrict__ pre,   // [2][L][B][1024]
    const unsigned short* __restrict__ whh,   // [2][1024][256] bf16
    unsigned short* __restrict__ hcat)        // [L][B][512] bf16
{
    __shared__ unsigned short h_lds[2][16][264];    // 256 + 8 pad
    __shared__ unsigned short pre_lds[16][1024];

    int wg = blockIdx.x;
    int d = wg >> 3, bb = wg & 7, b0 = bb * 16;
    int tid = threadIdx.x, w = tid >> 6, lane = tid & 63;
    int quad = lane >> 4, ln = lane & 15;
    const unsigned short* whh_d = whh + (size_t)d * G4H * H_;
    const unsigned short* pre_d = pre + (size_t)d * L_ * B_ * G4H;

    float c[4][4];
    #pragma unroll
    for (int a = 0; a < 4; ++a)
        #pragma unroll
        for (int r2 = 0; r2 < 4; ++r2) c[a][r2] = 0.f;

    for (int i = tid; i < 2 * 16 * 264; i += 256) ((unsigned short*)h_lds)[i] = 0;

    {   // preload pre[t=0]
        int l0 = (d == 0) ? 0 : (L_ - 1);
        const uint4* src = reinterpret_cast<const uint4*>(pre_d + ((size_t)l0 * B_ + b0) * G4H);
        uint4* dst = reinterpret_cast<uint4*>(&pre_lds[0][0]);
        #pragma unroll
        for (int i = 0; i < 8; ++i) dst[tid + i * 256] = src[tid + i * 256];
    }
    __syncthreads();

    for (int t = 0; t < L_; ++t) {
        int p = t & 1;
        int l = (d == 0) ? t : (L_ - 1 - t);
        int tn = (t + 1 < L_) ? (t + 1) : t;
        int lnext = (d == 0) ? tn : (L_ - 1 - tn);

        // prefetch pre[t+1] into regs (latency hidden behind MFMA)
        uint4 stage[8];
        const uint4* psrc = reinterpret_cast<const uint4*>(pre_d + ((size_t)lnext * B_ + b0) * G4H);
        #pragma unroll
        for (int i = 0; i < 8; ++i) stage[i] = psrc[tid + i * 256];

        f32x4 acc[16];
        #pragma unroll
        for (int i = 0; i < 16; ++i) acc[i] = (f32x4){0.f, 0.f, 0.f, 0.f};

        #pragma unroll
        for (int kc = 0; kc < 8; ++kc) {
            bf16x8 af = *reinterpret_cast<const bf16x8*>(&h_lds[p][ln][kc * 32 + quad * 8]);
            #pragma unroll
            for (int a = 0; a < 4; ++a) {
                #pragma unroll
                for (int g = 0; g < 4; ++g) {
                    int tile = 16 * g + w + 4 * a;
                    bf16x8 bfv = *reinterpret_cast<const bf16x8*>(
                        whh_d + (size_t)(tile * 16 + ln) * 256 + kc * 32 + quad * 8);
                    acc[a * 4 + g] = __builtin_amdgcn_mfma_f32_16x16x32_bf16(af, bfv, acc[a * 4 + g], 0, 0, 0);
                }
            }
        }

        #pragma unroll
        for (int a = 0; a < 4; ++a) {
            int j0 = 16 * (w + 4 * a) + ln;     // hidden column
            #pragma unroll
            for (int r2 = 0; r2 < 4; ++r2) {
                int m = quad * 4 + r2;          // batch-local row
                float gi = acc[a * 4 + 0][r2] + bf2f(pre_lds[m][j0]);
                float gf = acc[a * 4 + 1][r2] + bf2f(pre_lds[m][256 + j0]);
                float gg = acc[a * 4 + 2][r2] + bf2f(pre_lds[m][512 + j0]);
                float go = acc[a * 4 + 3][r2] + bf2f(pre_lds[m][768 + j0]);
                float cn = sigm(gf) * c[a][r2] + sigm(gi) * tanh_f(gg);
                c[a][r2] = cn;
                float hn = sigm(go) * tanh_f(cn);
                unsigned short hb = f2bf(hn);
                h_lds[p ^ 1][m][j0] = hb;
                hcat[((size_t)l * B_ + b0 + m) * (2 * H_) + d * H_ + j0] = hb;
            }
        }
        __syncthreads();   // all reads of pre_lds / writes of h_lds done
        {
            uint4* pdst = reinterpret_cast<uint4*>(&pre_lds[0][0]);
            #pragma unroll
            for (int i = 0; i < 8; ++i) pdst[tid + i * 256] = stage[i];
        }
        __syncthreads();   // pre_lds now holds pre[t+1]
    }
}

// ---------------------------------------------------------------------------
// emit[b][l][k] = hcat[l][b][:] . w_emit[k][:] + b_emit[k]   (fp32 out)
// ---------------------------------------------------------------------------
__global__ __launch_bounds__(256) void emit_gemm(
    const unsigned short* __restrict__ hcat,   // [L*B][512]
    const unsigned short* __restrict__ wemit,  // [64][512]
    const float* __restrict__ bemit,           // [64]
    float* __restrict__ emit)                  // [B][L][64]
{
    int m0 = blockIdx.x * 64;
    int tid = threadIdx.x, w = tid >> 6, lane = tid & 63;
    int quad = lane >> 4, ln = lane & 15;
    int mrow = m0 + w * 16;

    f32x4 acc[4];
    #pragma unroll
    for (int i = 0; i < 4; ++i) acc[i] = (f32x4){0.f, 0.f, 0.f, 0.f};

    const unsigned short* arow = hcat + (size_t)(mrow + ln) * 512;
    #pragma unroll 4
    for (int kc = 0; kc < 16; ++kc) {
        bf16x8 af = *reinterpret_cast<const bf16x8*>(arow + kc * 32 + quad * 8);
        #pragma unroll
        for (int T = 0; T < 4; ++T) {
            bf16x8 bfv = *reinterpret_cast<const bf16x8*>(wemit + (size_t)(T * 16 + ln) * 512 + kc * 32 + quad * 8);
            acc[T] = __builtin_amdgcn_mfma_f32_16x16x32_bf16(af, bfv, acc[T], 0, 0, 0);
        }
    }
    #pragma unroll
    for (int T = 0; T < 4; ++T) {
        int k = T * 16 + ln;
        float bias = bemit[k];
        #pragma unroll
        for (int rg = 0; rg < 4; ++rg) {
            int m = mrow + quad * 4 + rg;
            int ll = m >> 7, bidx = m & 127;
            emit[((size_t)bidx * L_ + ll) * K_ + k] = acc[T][rg] + bias;
        }
    }
}

// ---------------------------------------------------------------------------
// CRF: per batch row, 511 sequential steps.
// lse_i(d_i + T[i,k]) = M + log( sum_i exp(d_i - M) * expT[i][k] ),  M = max_i d_i
// expT precomputed -> each step: 1 exp + 64 FMA per lane.
// ---------------------------------------------------------------------------
__global__ __launch_bounds__(64) void crf_kernel(
    const float* __restrict__ emit,    // [B][L][64]
    const int* __restrict__ labels,    // [B][L]
    const float* __restrict__ trans,   // [64][64]
    float* __restrict__ out)           // [B]
{
    __shared__ float els[64];
    int b = blockIdx.x, lane = threadIdx.x;
    const float* eb = emit + (size_t)b * L_ * K_;
    const int* lb = labels + (size_t)b * L_;

    // gold score (emissions at labels + transitions)
    float gold = 0.f;
    for (int t = lane; t < L_; t += 64) gold += eb[(size_t)t * K_ + lb[t]];
    for (int t = lane; t < L_ - 1; t += 64) gold += trans[lb[t] * K_ + lb[t + 1]];
    #pragma unroll
    for (int off = 32; off; off >>= 1) gold += __shfl_down(gold, off);

    float expT[64];   // column `lane` of exp(T)
    #pragma unroll
    for (int i = 0; i < 64; ++i) expT[i] = __expf(trans[i * K_ + lane]);

    float dstate = eb[lane];
    float enext = eb[K_ + lane];
    for (int t = 1; t < L_; ++t) {
        float ecur = enext;
        if (t + 1 < L_) enext = eb[(size_t)(t + 1) * K_ + lane];
        float M = dstate;
        #pragma unroll
        for (int off = 32; off; off >>= 1) M = fmaxf(M, __shfl_xor(M, off));
        float e = __expf(dstate - M);
        __syncthreads();              // WAR on els
        els[lane] = e;
        __syncthreads();
        float s = 0.f;
        #pragma unroll
        for (int i = 0; i < 64; i += 4) {
            float4 ev = *reinterpret_cast<const float4*>(&els[i]);
            s = fmaf(ev.x, expT[i], s);
            s = fmaf(ev.y, expT[i + 1], s);
            s = fmaf(ev.z, expT[i + 2], s);
            s = fmaf(ev.w, expT[i + 3], s);
        }
        dstate = M + __logf(s) + ecur;
    }
    float M = dstate;
    #pragma unroll
    for (int off = 32; off; off >>= 1) M = fmaxf(M, __shfl_xor(M, off));
    float e = __expf(dstate - M);
    float s = e;
    #pragma unroll
    for (int off = 32; off; off >>= 1) s += __shfl_xor(s, off);
    float logZ = M + __logf(s);
    if (lane == 0) out[b] = -(gold - logZ);
}

// ---------------------------------------------------------------------------
// Workspace layout (bytes)
// ---------------------------------------------------------------------------
#define OFF_PRE    ((size_t)0)
#define OFF_HCAT   ((size_t)268435456)            // 2*512*128*1024*2
#define OFF_EMIT   ((size_t)(OFF_HCAT + 67108864))  // 512*128*512*2
#define OFF_WHH    ((size_t)(OFF_EMIT + 16777216))  // 128*512*64*4
#define OFF_WEMIT  ((size_t)(OFF_WHH + 1048576))
#define OFF_BIAS   ((size_t)(OFF_WEMIT + 65536))

extern "C" void kernel_launch(void* const* d_in, const int* in_sizes, int n_in,
                              void* d_out, int out_size, void* d_ws, size_t ws_size,
                              hipStream_t stream) {
    const float* x      = (const float*)d_in[0];
    const int*   labels = (const int*)d_in[1];
    const float* wihf   = (const float*)d_in[2];
    const float* whhf   = (const float*)d_in[3];
    const float* bihf   = (const float*)d_in[4];
    const float* bhhf   = (const float*)d_in[5];
    const float* wihb   = (const float*)d_in[6];
    const float* whhb   = (const float*)d_in[7];
    const float* bihb   = (const float*)d_in[8];
    const float* bhhb   = (const float*)d_in[9];
    const float* wemit  = (const float*)d_in[10];
    const float* bemit  = (const float*)d_in[11];
    const float* trans  = (const float*)d_in[12];
    float* out = (float*)d_out;

    char* ws = (char*)d_ws;
    unsigned short* pre    = (unsigned short*)(ws + OFF_PRE);
    unsigned short* hcat   = (unsigned short*)(ws + OFF_HCAT);
    float*          emit   = (float*)(ws + OFF_EMIT);
    unsigned short* whh_bf = (unsigned short*)(ws + OFF_WHH);
    unsigned short* we_bf  = (unsigned short*)(ws + OFF_WEMIT);
    float*          bias   = (float*)(ws + OFF_BIAS);

    setup_convert<<<2048, 256, 0, stream>>>(whhf, whhb, wemit, bihf, bhhf, bihb, bhhb,
                                            whh_bf, we_bf, bias);
    pre_gemm<<<dim3(32, 1024), 256, 0, stream>>>(x, wihf, wihb, bias, pre);
    lstm_scan<<<16, 256, 0, stream>>>(pre, whh_bf, hcat);
    emit_gemm<<<1024, 256, 0, stream>>>(hcat, we_bf, bemit, emit);
    crf_kernel<<<128, 64, 0, stream>>>(emit, labels, trans, out);
}

// Round 2
// 2109.498 us; speedup vs baseline: 3.8982x; 3.8982x over previous
//
#include <hip/hip_runtime.h>
#include <hip/hip_bf16.h>

#define B_   128
#define L_   512
#define E_   512
#define H_   256
#define K_   64
#define G4H  1024   // 4*H

typedef __bf16 bf16x8 __attribute__((ext_vector_type(8)));
typedef float  f32x4  __attribute__((ext_vector_type(4)));
typedef long long i64;

__device__ inline unsigned short f2bf(float f) {
    unsigned int x = __builtin_bit_cast(unsigned int, f);
    unsigned int r = (x + 0x7fffu + ((x >> 16) & 1u)) >> 16;
    return (unsigned short)r;
}
__device__ inline float bf2f(unsigned short u) {
    unsigned int x = ((unsigned int)u) << 16;
    return __builtin_bit_cast(float, x);
}
__device__ inline unsigned int pack2(float lo, float hi) {
    return (unsigned int)f2bf(lo) | ((unsigned int)f2bf(hi) << 16);
}

// ---------------------------------------------------------------------------
// Setup: w_hh (both dirs) -> fp8 e4m3; w_emit -> bf16; bias_cat = b_ih + b_hh
// ---------------------------------------------------------------------------
__global__ void setup_convert(const float* __restrict__ whh_f, const float* __restrict__ whh_b,
                              const float* __restrict__ wemit,
                              const float* __restrict__ bihf, const float* __restrict__ bhhf,
                              const float* __restrict__ bihb, const float* __restrict__ bhhb,
                              unsigned char* __restrict__ whh8,
                              unsigned short* __restrict__ wemit_bf,
                              float* __restrict__ bias_cat) {
    int i = blockIdx.x * 256 + threadIdx.x;
    // 2*1024*256 = 524288 fp8 values -> 262144 pairs
    if (i < 262144) {
        int j = 2 * i;
        float v0 = (j < 262144) ? whh_f[j] : whh_b[j - 262144];
        float v1 = (j + 1 < 262144) ? whh_f[j + 1] : whh_b[j + 1 - 262144];
        int pk = __builtin_amdgcn_cvt_pk_fp8_f32(v0, v1, 0, false);
        ((unsigned short*)whh8)[i] = (unsigned short)(pk & 0xffff);
    }
    if (i < K_ * 2 * H_) wemit_bf[i] = f2bf(wemit[i]);
    if (i < 2 * G4H) {
        bias_cat[i] = (i < G4H) ? (bihf[i] + bhhf[i]) : (bihb[i - G4H] + bhhb[i - G4H]);
    }
}

// ---------------------------------------------------------------------------
// pre2[d][l][bslice(16)][col(1024)][r(8)] (bf16):
//   pre2[...] = x[b][l][:] . w_ih_d[col][:] + bias_cat, with b = bslice*8 + r
// GEMM M = L*B (m = l*128+b), N = 2048 (d*1024+col), K = 512. 64x64 tiles.
// ---------------------------------------------------------------------------
__global__ __launch_bounds__(256) void pre_gemm(
    const float* __restrict__ x,       // (B,L,E)
    const float* __restrict__ wihf,    // (1024,512)
    const float* __restrict__ wihb,    // (1024,512)
    const float* __restrict__ bias_cat,// (2048)
    unsigned short* __restrict__ pre2)
{
    __shared__ unsigned short lds_a[64][40];   // 32 K-slice + 8 pad
    __shared__ unsigned short lds_b[64][40];

    int nt = blockIdx.x, mt = blockIdx.y;
    int tid = threadIdx.x;
    int n0 = nt * 64;
    int m0 = mt * 64;
    int l      = m0 >> 7;
    int b_base = m0 & 127;
    const float* wsrc = (n0 < 1024) ? (wihf + (size_t)n0 * E_) : (wihb + (size_t)(n0 - 1024) * E_);

    int w    = tid >> 6;
    int lane = tid & 63;
    int quad = lane >> 4, ln = lane & 15;
    int wm = (w >> 1) * 32, wn = (w & 1) * 32;

    f32x4 acc[2][2];
    #pragma unroll
    for (int i = 0; i < 2; ++i)
        #pragma unroll
        for (int j = 0; j < 2; ++j) acc[i][j] = (f32x4){0.f, 0.f, 0.f, 0.f};

    int r  = tid >> 2;          // staging row 0..63
    int kk = (tid & 3) * 8;     // staging k offset

    const float* arow = x + (size_t)(b_base + r) * L_ * E_ + (size_t)l * E_;
    const float* brow = wsrc + (size_t)r * E_;

    for (int kc = 0; kc < 16; ++kc) {
        int k0 = kc * 32;
        float4 a0 = *reinterpret_cast<const float4*>(arow + k0 + kk);
        float4 a1 = *reinterpret_cast<const float4*>(arow + k0 + kk + 4);
        float4 b0 = *reinterpret_cast<const float4*>(brow + k0 + kk);
        float4 b1 = *reinterpret_cast<const float4*>(brow + k0 + kk + 4);
        __syncthreads();   // WAR: previous iter frag reads done
        uint4 pa = { pack2(a0.x, a0.y), pack2(a0.z, a0.w), pack2(a1.x, a1.y), pack2(a1.z, a1.w) };
        uint4 pb = { pack2(b0.x, b0.y), pack2(b0.z, b0.w), pack2(b1.x, b1.y), pack2(b1.z, b1.w) };
        *reinterpret_cast<uint4*>(&lds_a[r][kk]) = pa;
        *reinterpret_cast<uint4*>(&lds_b[r][kk]) = pb;
        __syncthreads();

        bf16x8 af[2], bfv[2];
        #pragma unroll
        for (int ms = 0; ms < 2; ++ms)
            af[ms] = *reinterpret_cast<const bf16x8*>(&lds_a[wm + ms * 16 + ln][quad * 8]);
        #pragma unroll
        for (int ns = 0; ns < 2; ++ns)
            bfv[ns] = *reinterpret_cast<const bf16x8*>(&lds_b[wn + ns * 16 + ln][quad * 8]);
        #pragma unroll
        for (int ms = 0; ms < 2; ++ms)
            #pragma unroll
            for (int ns = 0; ns < 2; ++ns)
                acc[ms][ns] = __builtin_amdgcn_mfma_f32_16x16x32_bf16(af[ms], bfv[ns], acc[ms][ns], 0, 0, 0);
    }

    #pragma unroll
    for (int ns = 0; ns < 2; ++ns) {
        int n = n0 + wn + ns * 16 + ln;
        float bias = bias_cat[n];
        int col = n & 1023, dsel = n >> 10;
        #pragma unroll
        for (int ms = 0; ms < 2; ++ms) {
            int m_base = m0 + wm + ms * 16 + quad * 4;   // + rg (0..3), same l & bslice
            int ll = m_base >> 7;
            int b  = m_base & 127;
            int bslice = b >> 3, r0 = b & 7;             // r0 in {0,4}
            ushort4 v;
            v.x = f2bf(acc[ms][ns][0] + bias);
            v.y = f2bf(acc[ms][ns][1] + bias);
            v.z = f2bf(acc[ms][ns][2] + bias);
            v.w = f2bf(acc[ms][ns][3] + bias);
            *reinterpret_cast<ushort4*>(
                &pre2[((((size_t)dsel * L_ + ll) * 16 + bslice) * 1024 + col) * 8 + r0]) = v;
        }
    }
}

// ---------------------------------------------------------------------------
// LSTM scan, fp8 W_hh register-resident.
// 32 WGs: d = wg>>4, bslice = wg&15 (8 batch rows). 512 threads = 8 waves.
// Wave w owns tiles T = g*16 + w + 8*s (g=gate 0..3, s=0..1) -> 8 tiles,
// fp8 B-frags held in 128 VGPRs. Per step: MFMA (M=8 in 16-row tiles),
// G -> LDS, balanced activation over all 512 threads, h -> fp8 LDS + bf16 hcat.
// ---------------------------------------------------------------------------
__global__ __launch_bounds__(512, 2) void lstm_scan(
    const unsigned short* __restrict__ pre2,  // [2][512][16][1024][8] bf16
    const unsigned char* __restrict__ whh8,   // [2][1024][256] fp8 e4m3
    unsigned short* __restrict__ hcat)        // [512][128][512] bf16
{
    __shared__ unsigned char  h_lds[2][16][264];            // fp8, rows 8..15 stay 0
    __shared__ unsigned short pre_lds[1024 * 8 + 128 * 8];  // [col][8] + 16B pad/8 cols
    __shared__ float          g_lds[1024 * 8 + 128 * 8];    // [col][8] + pad

    int wg = blockIdx.x;
    int d = wg >> 4, bs = wg & 15, b0 = bs * 8;
    int tid = threadIdx.x, w = tid >> 6, lane = tid & 63;
    int q = lane >> 4, ln = lane & 15;

    const unsigned char* whh_d = whh8 + (size_t)d * (1024 * 256);
    const unsigned short* pre_wg = pre2 + ((size_t)d * 512 * 16 + bs) * 8192;

    // ---- W_hh fragments into registers: wh[a][kc], a = g*2+s ----
    i64 wh[8][8];
    #pragma unroll
    for (int a = 0; a < 8; ++a) {
        int T = (a >> 1) * 16 + w + 8 * (a & 1);
        #pragma unroll
        for (int kc = 0; kc < 8; ++kc)
            wh[a][kc] = *reinterpret_cast<const i64*>(
                whh_d + (size_t)(T * 16 + ln) * 256 + kc * 32 + q * 8);
    }

    // zero h_lds (both buffers, all 16 rows)
    for (int i = tid; i < (2 * 16 * 264) / 4; i += 512) ((int*)h_lds)[i] = 0;

    // stage pre[t=0]
    {
        int l0 = (d == 0) ? 0 : (L_ - 1);
        const uint4* src = reinterpret_cast<const uint4*>(pre_wg + (size_t)l0 * 131072);
        uint4 s0 = src[tid * 2], s1 = src[tid * 2 + 1];
        int c0 = tid * 2;
        int off = c0 * 8 + (c0 >> 3) * 8;
        *reinterpret_cast<uint4*>(&pre_lds[off]) = s0;
        *reinterpret_cast<uint4*>(&pre_lds[off + 8]) = s1;
    }
    __syncthreads();

    float cst[4] = {0.f, 0.f, 0.f, 0.f};
    int ac  = tid & 255;          // activation hidden column 0..255
    int ar0 = (tid >> 8) * 4;     // activation rows ar0..ar0+3 (0 or 4)

    for (int t = 0; t < L_; ++t) {
        int p = t & 1;
        int l = (d == 0) ? t : (L_ - 1 - t);
        int tn = (t + 1 < L_) ? (t + 1) : t;
        int lnext = (d == 0) ? tn : (L_ - 1 - tn);

        // prefetch pre[t+1] into regs
        uint4 st0, st1;
        {
            const uint4* src = reinterpret_cast<const uint4*>(pre_wg + (size_t)lnext * 131072);
            st0 = src[tid * 2]; st1 = src[tid * 2 + 1];
        }

        // ---- MFMA: G = h @ W_hh^T ----
        f32x4 acc[8];
        #pragma unroll
        for (int a = 0; a < 8; ++a) acc[a] = (f32x4){0.f, 0.f, 0.f, 0.f};
        #pragma unroll
        for (int kc = 0; kc < 8; ++kc) {
            i64 af = *reinterpret_cast<const i64*>(&h_lds[p][ln][kc * 32 + q * 8]);
            #pragma unroll
            for (int a = 0; a < 8; ++a)
                acc[a] = __builtin_amdgcn_mfma_f32_16x16x32_fp8_fp8(af, wh[a][kc], acc[a], 0, 0, 0);
        }
        // scatter G to LDS (valid rows = quads 0,1)
        if (q < 2) {
            #pragma unroll
            for (int a = 0; a < 8; ++a) {
                int T = (a >> 1) * 16 + w + 8 * (a & 1);
                int col = T * 16 + ln;
                *reinterpret_cast<f32x4*>(&g_lds[col * 8 + (col >> 3) * 8 + q * 4]) = acc[a];
            }
        }
        __syncthreads();

        // ---- balanced activation: thread -> (col=ac, rows ar0..ar0+3) ----
        f32x4 Gv[4];
        unsigned short pv[4][4];
        #pragma unroll
        for (int g = 0; g < 4; ++g) {
            int col = g * 256 + ac;
            int off = col * 8 + (col >> 3) * 8;
            Gv[g] = *reinterpret_cast<const f32x4*>(&g_lds[off + ar0]);
            ushort4 P = *reinterpret_cast<const ushort4*>(&pre_lds[off + ar0]);
            pv[g][0] = P.x; pv[g][1] = P.y; pv[g][2] = P.z; pv[g][3] = P.w;
        }
        float hn[4];
        #pragma unroll
        for (int i2 = 0; i2 < 4; ++i2) {
            float vi = Gv[0][i2] + bf2f(pv[0][i2]);
            float vf = Gv[1][i2] + bf2f(pv[1][i2]);
            float vg = Gv[2][i2] + bf2f(pv[2][i2]);
            float vo = Gv[3][i2] + bf2f(pv[3][i2]);
            float ei  = __expf(vi);
            float e2g = __expf(2.f * vg);
            float ef  = __expf(vf);
            float eo  = __expf(vo);
            // sigm(f)*c + sigm(i)*tanh(g), with one rcp per pair
            float fs = ef * __builtin_amdgcn_rcpf(1.f + ef);
            float itg = (ei * (e2g - 1.f)) * __builtin_amdgcn_rcpf((1.f + ei) * (1.f + e2g));
            float cn = fs * cst[i2] + itg;
            cst[i2] = cn;
            float e2c = __expf(2.f * cn);
            hn[i2] = (eo * (e2c - 1.f)) * __builtin_amdgcn_rcpf((1.f + eo) * (1.f + e2c));
        }
        // h -> fp8 (next MFMA input) and bf16 hcat
        int pk01 = __builtin_amdgcn_cvt_pk_fp8_f32(hn[0], hn[1], 0, false);
        int pk23 = __builtin_amdgcn_cvt_pk_fp8_f32(hn[2], hn[3], 0, false);
        unsigned char hq[4] = { (unsigned char)(pk01 & 0xff), (unsigned char)((pk01 >> 8) & 0xff),
                                (unsigned char)(pk23 & 0xff), (unsigned char)((pk23 >> 8) & 0xff) };
        #pragma unroll
        for (int i2 = 0; i2 < 4; ++i2) {
            h_lds[p ^ 1][ar0 + i2][ac] = hq[i2];
            hcat[((size_t)l * B_ + b0 + ar0 + i2) * (2 * H_) + d * H_ + ac] = f2bf(hn[i2]);
        }
        __syncthreads();   // h_lds[p^1] ready; pre_lds/g_lds reads done

        // stage -> pre_lds (visible after next iter's first barrier)
        {
            int c0 = tid * 2;
            int off = c0 * 8 + (c0 >> 3) * 8;
            *reinterpret_cast<uint4*>(&pre_lds[off]) = st0;
            *reinterpret_cast<uint4*>(&pre_lds[off + 8]) = st1;
        }
    }
}

// ---------------------------------------------------------------------------
// emit[b][l][k] = hcat[l][b][:] . w_emit[k][:] + b_emit[k]   (fp32 out)
// ---------------------------------------------------------------------------
__global__ __launch_bounds__(256) void emit_gemm(
    const unsigned short* __restrict__ hcat,   // [L*B][512]
    const unsigned short* __restrict__ wemit,  // [64][512]
    const float* __restrict__ bemit,           // [64]
    float* __restrict__ emit)                  // [B][L][64]
{
    int m0 = blockIdx.x * 64;
    int tid = threadIdx.x, w = tid >> 6, lane = tid & 63;
    int quad = lane >> 4, ln = lane & 15;
    int mrow = m0 + w * 16;

    f32x4 acc[4];
    #pragma unroll
    for (int i = 0; i < 4; ++i) acc[i] = (f32x4){0.f, 0.f, 0.f, 0.f};

    const unsigned short* arow = hcat + (size_t)(mrow + ln) * 512;
    #pragma unroll 4
    for (int kc = 0; kc < 16; ++kc) {
        bf16x8 af = *reinterpret_cast<const bf16x8*>(arow + kc * 32 + quad * 8);
        #pragma unroll
        for (int T = 0; T < 4; ++T) {
            bf16x8 bfv = *reinterpret_cast<const bf16x8*>(wemit + (size_t)(T * 16 + ln) * 512 + kc * 32 + quad * 8);
            acc[T] = __builtin_amdgcn_mfma_f32_16x16x32_bf16(af, bfv, acc[T], 0, 0, 0);
        }
    }
    #pragma unroll
    for (int T = 0; T < 4; ++T) {
        int k = T * 16 + ln;
        float bias = bemit[k];
        #pragma unroll
        for (int rg = 0; rg < 4; ++rg) {
            int m = mrow + quad * 4 + rg;
            int ll = m >> 7, bidx = m & 127;
            emit[((size_t)bidx * L_ + ll) * K_ + k] = acc[T][rg] + bias;
        }
    }
}

// ---------------------------------------------------------------------------
// CRF: per batch row, 511 sequential steps.
// lse_i(d_i + T[i,k]) = M + log( sum_i exp(d_i - M) * expT[i][k] ),  M = max_i d_i
// ---------------------------------------------------------------------------
__global__ __launch_bounds__(64) void crf_kernel(
    const float* __restrict__ emit,    // [B][L][64]
    const int* __restrict__ labels,    // [B][L]
    const float* __restrict__ trans,   // [64][64]
    float* __restrict__ out)           // [B]
{
    __shared__ float els[64];
    int b = blockIdx.x, lane = threadIdx.x;
    const float* eb = emit + (size_t)b * L_ * K_;
    const int* lb = labels + (size_t)b * L_;

    float gold = 0.f;
    for (int t = lane; t < L_; t += 64) gold += eb[(size_t)t * K_ + lb[t]];
    for (int t = lane; t < L_ - 1; t += 64) gold += trans[lb[t] * K_ + lb[t + 1]];
    #pragma unroll
    for (int off = 32; off; off >>= 1) gold += __shfl_down(gold, off);

    float expT[64];   // column `lane` of exp(T)
    #pragma unroll
    for (int i = 0; i < 64; ++i) expT[i] = __expf(trans[i * K_ + lane]);

    float dstate = eb[lane];
    float enext = eb[K_ + lane];
    for (int t = 1; t < L_; ++t) {
        float ecur = enext;
        if (t + 1 < L_) enext = eb[(size_t)(t + 1) * K_ + lane];
        float M = dstate;
        #pragma unroll
        for (int off = 32; off; off >>= 1) M = fmaxf(M, __shfl_xor(M, off));
        float e = __expf(dstate - M);
        __syncthreads();              // WAR on els
        els[lane] = e;
        __syncthreads();
        float s = 0.f;
        #pragma unroll
        for (int i = 0; i < 64; i += 4) {
            float4 ev = *reinterpret_cast<const float4*>(&els[i]);
            s = fmaf(ev.x, expT[i], s);
            s = fmaf(ev.y, expT[i + 1], s);
            s = fmaf(ev.z, expT[i + 2], s);
            s = fmaf(ev.w, expT[i + 3], s);
        }
        dstate = M + __logf(s) + ecur;
    }
    float M = dstate;
    #pragma unroll
    for (int off = 32; off; off >>= 1) M = fmaxf(M, __shfl_xor(M, off));
    float e = __expf(dstate - M);
    float s = e;
    #pragma unroll
    for (int off = 32; off; off >>= 1) s += __shfl_xor(s, off);
    float logZ = M + __logf(s);
    if (lane == 0) out[b] = -(gold - logZ);
}

// ---------------------------------------------------------------------------
// Workspace layout (bytes)
// ---------------------------------------------------------------------------
#define OFF_PRE    ((size_t)0)                       // 2*512*16*1024*8*2 = 268435456
#define OFF_HCAT   ((size_t)268435456)               // 512*128*512*2     =  67108864
#define OFF_EMIT   ((size_t)(OFF_HCAT + 67108864))   // 128*512*64*4      =  16777216
#define OFF_WHH8   ((size_t)(OFF_EMIT + 16777216))   // 2*1024*256        =    524288
#define OFF_WEMIT  ((size_t)(OFF_WHH8 + 524288))     // 64*512*2          =     65536
#define OFF_BIAS   ((size_t)(OFF_WEMIT + 65536))     // 2048*4

extern "C" void kernel_launch(void* const* d_in, const int* in_sizes, int n_in,
                              void* d_out, int out_size, void* d_ws, size_t ws_size,
                              hipStream_t stream) {
    const float* x      = (const float*)d_in[0];
    const int*   labels = (const int*)d_in[1];
    const float* wihf   = (const float*)d_in[2];
    const float* whhf   = (const float*)d_in[3];
    const float* bihf   = (const float*)d_in[4];
    const float* bhhf   = (const float*)d_in[5];
    const float* wihb   = (const float*)d_in[6];
    const float* whhb   = (const float*)d_in[7];
    const float* bihb   = (const float*)d_in[8];
    const float* bhhb   = (const float*)d_in[9];
    const float* wemit  = (const float*)d_in[10];
    const float* bemit  = (const float*)d_in[11];
    const float* trans  = (const float*)d_in[12];
    float* out = (float*)d_out;

    char* ws = (char*)d_ws;
    unsigned short* pre2   = (unsigned short*)(ws + OFF_PRE);
    unsigned short* hcat   = (unsigned short*)(ws + OFF_HCAT);
    float*          emit   = (float*)(ws + OFF_EMIT);
    unsigned char*  whh8   = (unsigned char*)(ws + OFF_WHH8);
    unsigned short* we_bf  = (unsigned short*)(ws + OFF_WEMIT);
    float*          bias   = (float*)(ws + OFF_BIAS);

    setup_convert<<<2048, 256, 0, stream>>>(whhf, whhb, wemit, bihf, bhhf, bihb, bhhb,
                                            whh8, we_bf, bias);
    pre_gemm<<<dim3(32, 1024), 256, 0, stream>>>(x, wihf, wihb, bias, pre2);
    lstm_scan<<<32, 512, 0, stream>>>(pre2, whh8, hcat);
    emit_gemm<<<1024, 256, 0, stream>>>(hcat, we_bf, bemit, emit);
    crf_kernel<<<128, 64, 0, stream>>>(emit, labels, trans, out);
}